// Round 2
// baseline (1081.946 us; speedup 1.0000x reference)
//
#include <hip/hip_runtime.h>

namespace {
constexpr int NB = 128;       // batch
constexpr int NR = 512;       // residues
constexpr int ND = 256;       // VDIM
constexpr int NA = 14;        // MAXA
constexpr int BC = 8;         // batches per block
constexpr int NC = BC * 3;    // 24 columns (b,c pairs) per block
constexpr int NBCH = NB / BC; // 16 batch-chunks
}

// One block = one residue r x 8 batches. 256 threads, thread == v-row.
// h ping-pong in LDS: hA/hB are [v][n], n = bb*3 + c.
__global__ __launch_bounds__(256, 3) void residues_fused(
    const float* __restrict__ x, const float* __restrict__ W0,
    const float* __restrict__ Wh, const int* __restrict__ type_ids,
    const int* __restrict__ res_idx, float* __restrict__ out, int n_atoms)
{
    const int tid = threadIdx.x;
    const int r = blockIdx.x >> 4;          // 16 batch-chunks per residue
    const int b0 = (blockIdx.x & 15) * BC;

    const int ri = res_idx[r];
    const int t  = type_ids[r];

    __shared__ float dlt[NA][NC];   // delta, staged: [a][bb*3+c]
    __shared__ float hA[ND][NC];
    __shared__ float hB[ND][NC];

    // ---- stage delta, write pos_ca --------------------------------------
    // 336 elements > 256 threads: MUST stride (round-1 bug: bb=6/7 unstaged)
    for (int idx = tid; idx < BC * NA * 3; idx += 256) {
        const int bb  = idx / (NA * 3);
        const int rem = idx % (NA * 3);
        const int a = rem / 3, c = rem % 3;
        const int b = b0 + bb;
        int ca = ri + a;
        if (ca > n_atoms - 1) ca = n_atoms - 1;   // clip (W0 pad-mask zeroes a>=natoms)
        const float root = x[((size_t)b * n_atoms + (ri + 1)) * 3 + c];
        const float g    = x[((size_t)b * n_atoms + ca) * 3 + c];
        dlt[a][bb * 3 + c] = g - root;
        if (a == 0) out[((size_t)b * NR + r) * 3 + c] = root;  // pos_ca
    }
    __syncthreads();

    // ---- layer 0: hA[v][n] = sum_a W0[t][v][a] * dlt[a][n] ---------------
    {
        const float* w0row = W0 + ((size_t)t * ND + tid) * NA;
        float acc[NC];
#pragma unroll
        for (int n = 0; n < NC; ++n) acc[n] = 0.f;
#pragma unroll
        for (int a = 0; a < NA; ++a) {
            const float w = w0row[a];
#pragma unroll
            for (int n4 = 0; n4 < NC; n4 += 4) {
                const float4 d4 = *reinterpret_cast<const float4*>(&dlt[a][n4]);
                acc[n4 + 0] += w * d4.x;
                acc[n4 + 1] += w * d4.y;
                acc[n4 + 2] += w * d4.z;
                acc[n4 + 3] += w * d4.w;
            }
        }
#pragma unroll
        for (int n = 0; n < NC; ++n) hA[tid][n] = acc[n];
    }
    __syncthreads();

    // ---- layers 1..2: hout[v][n] = sum_u Wh[t][l][v][u] * hin[u][n] ------
    const float* whbase = Wh + (size_t)t * 2 * ND * ND;
#pragma unroll
    for (int l = 0; l < 2; ++l) {
        const float* wrow = whbase + ((size_t)l * ND + tid) * ND;  // thread's v-row
        const float (*hin)[NC] = (l == 0) ? hA : hB;
        float (*hout)[NC]      = (l == 0) ? hB : hA;
        float acc[NC];
#pragma unroll
        for (int n = 0; n < NC; ++n) acc[n] = 0.f;
        for (int u0 = 0; u0 < ND; u0 += 4) {
            const float4 w4 = *reinterpret_cast<const float4*>(wrow + u0);
#pragma unroll
            for (int uu = 0; uu < 4; ++uu) {
                const float w = (uu == 0) ? w4.x : (uu == 1) ? w4.y : (uu == 2) ? w4.z : w4.w;
#pragma unroll
                for (int n4 = 0; n4 < NC; n4 += 4) {
                    const float4 h4 = *reinterpret_cast<const float4*>(&hin[u0 + uu][n4]);
                    acc[n4 + 0] += w * h4.x;
                    acc[n4 + 1] += w * h4.y;
                    acc[n4 + 2] += w * h4.z;
                    acc[n4 + 3] += w * h4.w;
                }
            }
        }
#pragma unroll
        for (int n = 0; n < NC; ++n) hout[tid][n] = acc[n];
        __syncthreads();
    }

    // ---- coalesced writeout of hA (final h) ------------------------------
    float* outh = out + (size_t)NB * NR * 3;
#pragma unroll
    for (int bb = 0; bb < BC; ++bb) {
        const size_t base = ((size_t)((b0 + bb) * NR + r)) * (ND * 3);
#pragma unroll
        for (int it = 0; it < 3; ++it) {
            const int g = it * 256 + tid;     // 0..767 within (b,r) region
            outh[base + g] = hA[g / 3][bb * 3 + g % 3];
        }
    }
}

extern "C" void kernel_launch(void* const* d_in, const int* in_sizes, int n_in,
                              void* d_out, int out_size, void* d_ws, size_t ws_size,
                              hipStream_t stream) {
    const float* x        = (const float*)d_in[0];
    const float* W0       = (const float*)d_in[1];
    const float* Wh       = (const float*)d_in[2];
    const int*   type_ids = (const int*)d_in[3];
    const int*   res_idx  = (const int*)d_in[4];
    float* out = (float*)d_out;

    const int n_atoms = in_sizes[0] / (NB * 3);

    dim3 grid(NR * NBCH);
    residues_fused<<<grid, 256, 0, stream>>>(x, W0, Wh, type_ids, res_idx, out, n_atoms);
}

// Round 3
// 148.493 us; speedup vs baseline: 7.2862x; 7.2862x over previous
//
#include <hip/hip_runtime.h>

namespace {
constexpr int NB = 128;
constexpr int NR = 512;
constexpr int ND = 256;
constexpr int NA = 14;

using short8 = __attribute__((ext_vector_type(8))) short;
using f32x4  = __attribute__((ext_vector_type(4))) float;

// swizzled-weight workspace layout (ushort elements)
constexpr size_t WH_US  = (size_t)40 * 16 * 8 * 64 * 8;   // 2,621,440
constexpr size_t W0_OFF = WH_US;                          // W0 after Wh
constexpr size_t W0_US  = (size_t)20 * 16 * 64 * 8;       // 163,840
constexpr size_t WS_NEEDED = (WH_US + W0_US) * 2;         // bytes = 5,570,560

__device__ __forceinline__ unsigned short f2bf(float f) {
    unsigned int u = __float_as_uint(f);
    u = (u + 0x7FFFu + ((u >> 16) & 1u)) >> 16;           // RNE
    return (unsigned short)u;
}
}

// ---- converter: Wh fp32 -> bf16, A-fragment order ---------------------------
// idx = ((tl*16 + mt)*8 + kt)*64 + lane ; lane holds W[tl][v=mt*16+(l&15)][u=kt*32+(l>>4)*8 + j]
__global__ void conv_wh(const float* __restrict__ Wh, unsigned short* __restrict__ ws) {
    int g = blockIdx.x * 256 + threadIdx.x;
    if (g >= 40 * 16 * 8 * 64) return;
    const int lane = g & 63, kt = (g >> 6) & 7, mt = (g >> 9) & 15, tl = g >> 13;
    const int v = mt * 16 + (lane & 15);
    const int u0 = kt * 32 + (lane >> 4) * 8;
    const float* src = Wh + ((size_t)tl * ND + v) * ND + u0;
    unsigned short o[8];
#pragma unroll
    for (int j = 0; j < 8; ++j) o[j] = f2bf(src[j]);
    uint4 pk;
    pk.x = o[0] | ((unsigned)o[1] << 16); pk.y = o[2] | ((unsigned)o[3] << 16);
    pk.z = o[4] | ((unsigned)o[5] << 16); pk.w = o[6] | ((unsigned)o[7] << 16);
    *reinterpret_cast<uint4*>(ws + (size_t)g * 8) = pk;
}

// W0: idx = ((t*16+mt)*64 + lane)*8 + j ; k = (l>>4)*8+j, zero-padded k>=14
__global__ void conv_w0(const float* __restrict__ W0, unsigned short* __restrict__ ws) {
    int g = blockIdx.x * 256 + threadIdx.x;
    if (g >= 20 * 16 * 64) return;
    const int lane = g & 63, mt = (g >> 6) & 15, t = g >> 10;
    const int v = mt * 16 + (lane & 15);
    const int a0 = (lane >> 4) * 8;
    unsigned short o[8];
#pragma unroll
    for (int j = 0; j < 8; ++j) {
        const int a = a0 + j;
        o[j] = (a < NA) ? f2bf(W0[((size_t)t * ND + v) * NA + a]) : (unsigned short)0;
    }
    uint4 pk;
    pk.x = o[0] | ((unsigned)o[1] << 16); pk.y = o[2] | ((unsigned)o[3] << 16);
    pk.z = o[4] | ((unsigned)o[5] << 16); pk.w = o[6] | ((unsigned)o[7] << 16);
    *reinterpret_cast<uint4*>(ws + W0_OFF + (size_t)g * 8) = pk;
}

// ---- main fused kernel ------------------------------------------------------
// block = (residue r, 32-batch column chunk) ; 96 GEMM columns n=(b-b0)*3+c
// 4 waves split M (v): wave w owns v in [64w, 64w+64)
__global__ __launch_bounds__(256, 3) void residues_mfma(
    const float* __restrict__ x, const unsigned short* __restrict__ wsw,
    const int* __restrict__ type_ids, const int* __restrict__ res_idx,
    float* __restrict__ out, int n_atoms)
{
    const int tid = threadIdx.x, lane = tid & 63, w = tid >> 6;
    const int r = blockIdx.x >> 2, b0 = (blockIdx.x & 3) * 32;
    const int ri = res_idx[r], t = type_ids[r];

    // HT[96][264] bf16 (row stride 528B -> 2-way banks, free). dltT[96][40] and
    // the fp32 epilogue stage [96][132] both alias this buffer (lifetimes disjoint).
    __shared__ __align__(16) unsigned short HT[96 * 264];
    unsigned short* dltT = HT;

    // ---- stage dltT (bf16, k padded to 32 with zeros) + pos_ca -------------
    for (int i = tid; i < 96 * 32; i += 256) {
        const int n = i >> 5, k = i & 31;
        const int b = b0 + n / 3, c = n % 3;
        float val = 0.f;
        if (k < NA) {
            int atom = ri + k; if (atom > n_atoms - 1) atom = n_atoms - 1;
            const float root = x[((size_t)b * n_atoms + ri + 1) * 3 + c];
            val = x[((size_t)b * n_atoms + atom) * 3 + c] - root;
        }
        dltT[n * 40 + k] = f2bf(val);
    }
    if (tid < 96) {
        const int b = b0 + tid / 3, c = tid % 3;
        out[((size_t)b * NR + r) * 3 + c] = x[((size_t)b * n_atoms + ri + 1) * 3 + c];
    }
    __syncthreads();

    f32x4 acc[4][6];
#pragma unroll
    for (int mi = 0; mi < 4; ++mi)
#pragma unroll
        for (int ni = 0; ni < 6; ++ni) acc[mi][ni] = f32x4{0.f, 0.f, 0.f, 0.f};

    // ---- layer 0: K=32 (padded), A from W0sw, B from dltT ------------------
    {
        const unsigned short* w0b = wsw + W0_OFF + (size_t)t * (16 * 64 * 8);
        short8 a[4], bf[6];
#pragma unroll
        for (int mi = 0; mi < 4; ++mi)
            a[mi] = *reinterpret_cast<const short8*>(w0b + (((w * 4 + mi) * 64) + lane) * 8);
#pragma unroll
        for (int ni = 0; ni < 6; ++ni)
            bf[ni] = *reinterpret_cast<const short8*>(&dltT[(ni * 16 + (lane & 15)) * 40 + (lane >> 4) * 8]);
#pragma unroll
        for (int mi = 0; mi < 4; ++mi)
#pragma unroll
            for (int ni = 0; ni < 6; ++ni)
                acc[mi][ni] = __builtin_amdgcn_mfma_f32_16x16x32_bf16(a[mi], bf[ni], acc[mi][ni], 0, 0, 0);
    }
    __syncthreads();

    // ---- hidden layers: acc -> HT (bf16), then GEMM from HT ----------------
#pragma unroll 1
    for (int l = 0; l < 2; ++l) {
        // write previous layer's output into HT[n][v]
#pragma unroll
        for (int mi = 0; mi < 4; ++mi)
#pragma unroll
            for (int ni = 0; ni < 6; ++ni) {
                const int v0 = w * 64 + mi * 16 + (lane >> 4) * 4;
                const int n  = ni * 16 + (lane & 15);
                const unsigned lo = (unsigned)f2bf(acc[mi][ni][0]) | ((unsigned)f2bf(acc[mi][ni][1]) << 16);
                const unsigned hi = (unsigned)f2bf(acc[mi][ni][2]) | ((unsigned)f2bf(acc[mi][ni][3]) << 16);
                *reinterpret_cast<uint2*>(&HT[n * 264 + v0]) = make_uint2(lo, hi);
            }
        __syncthreads();

#pragma unroll
        for (int mi = 0; mi < 4; ++mi)
#pragma unroll
            for (int ni = 0; ni < 6; ++ni) acc[mi][ni] = f32x4{0.f, 0.f, 0.f, 0.f};

        const unsigned short* wl = wsw + (size_t)(t * 2 + l) * (16 * 8 * 64 * 8);
        for (int kt = 0; kt < 8; ++kt) {
            short8 a[4], bf[6];
#pragma unroll
            for (int mi = 0; mi < 4; ++mi)
                a[mi] = *reinterpret_cast<const short8*>(wl + ((((w * 4 + mi) * 8 + kt) * 64) + lane) * 8);
#pragma unroll
            for (int ni = 0; ni < 6; ++ni)
                bf[ni] = *reinterpret_cast<const short8*>(&HT[(ni * 16 + (lane & 15)) * 264 + kt * 32 + (lane >> 4) * 8]);
#pragma unroll
            for (int mi = 0; mi < 4; ++mi)
#pragma unroll
                for (int ni = 0; ni < 6; ++ni)
                    acc[mi][ni] = __builtin_amdgcn_mfma_f32_16x16x32_bf16(a[mi], bf[ni], acc[mi][ni], 0, 0, 0);
        }
        if (l == 0) __syncthreads();   // all waves done reading HT before rewrite
    }

    // ---- epilogue: fp32 restage through LDS, coalesced float4 stores -------
    float* fst  = reinterpret_cast<float*>(HT);         // [96][132]
    float* outh = out + (size_t)NB * NR * 3;
#pragma unroll 1
    for (int p = 0; p < 2; ++p) {
        __syncthreads();
        if ((w >> 1) == p) {
            const int wl_ = w & 1;
#pragma unroll
            for (int mi = 0; mi < 4; ++mi)
#pragma unroll
                for (int ni = 0; ni < 6; ++ni) {
                    const int n = ni * 16 + (lane & 15);
#pragma unroll
                    for (int j = 0; j < 4; ++j) {
                        const int vl = wl_ * 64 + mi * 16 + (lane >> 4) * 4 + j;
                        fst[n * 132 + vl] = acc[mi][ni][j];
                    }
                }
        }
        __syncthreads();
#pragma unroll
        for (int i = 0; i < 12; ++i) {
            const int idx = tid + i * 256;        // 0..3071
            const int bl = idx / 96, g = idx % 96;
            float vv[4];
#pragma unroll
            for (int e = 0; e < 4; ++e) {
                const int f = 4 * g + e, c = f % 3, vp = f / 3;
                vv[e] = fst[(bl * 3 + c) * 132 + vp];
            }
            *reinterpret_cast<float4*>(&outh[(((size_t)(b0 + bl) * NR + r) * (ND * 3)) + p * 384 + 4 * g]) =
                make_float4(vv[0], vv[1], vv[2], vv[3]);
        }
    }
}

// ---- fallback (round-2 verified VALU kernel) if ws too small ---------------
__global__ __launch_bounds__(256, 3) void residues_fused_fb(
    const float* __restrict__ x, const float* __restrict__ W0,
    const float* __restrict__ Wh, const int* __restrict__ type_ids,
    const int* __restrict__ res_idx, float* __restrict__ out, int n_atoms)
{
    const int tid = threadIdx.x;
    const int r = blockIdx.x >> 4;
    const int b0 = (blockIdx.x & 15) * 8;
    const int ri = res_idx[r], t = type_ids[r];
    __shared__ float dlt[NA][24];
    __shared__ float hA[ND][24];
    __shared__ float hB[ND][24];
    for (int idx = tid; idx < 8 * NA * 3; idx += 256) {
        const int bb = idx / (NA * 3), rem = idx % (NA * 3);
        const int a = rem / 3, c = rem % 3, b = b0 + bb;
        int ca = ri + a; if (ca > n_atoms - 1) ca = n_atoms - 1;
        const float root = x[((size_t)b * n_atoms + (ri + 1)) * 3 + c];
        dlt[a][bb * 3 + c] = x[((size_t)b * n_atoms + ca) * 3 + c] - root;
        if (a == 0) out[((size_t)b * NR + r) * 3 + c] = root;
    }
    __syncthreads();
    {
        const float* w0row = W0 + ((size_t)t * ND + tid) * NA;
        float acc[24];
#pragma unroll
        for (int n = 0; n < 24; ++n) acc[n] = 0.f;
#pragma unroll
        for (int a = 0; a < NA; ++a) {
            const float wv = w0row[a];
#pragma unroll
            for (int n = 0; n < 24; ++n) acc[n] += wv * dlt[a][n];
        }
#pragma unroll
        for (int n = 0; n < 24; ++n) hA[tid][n] = acc[n];
    }
    __syncthreads();
    const float* whbase = Wh + (size_t)t * 2 * ND * ND;
#pragma unroll
    for (int l = 0; l < 2; ++l) {
        const float* wrow = whbase + ((size_t)l * ND + tid) * ND;
        const float (*hin)[24] = (l == 0) ? hA : hB;
        float (*hout)[24]      = (l == 0) ? hB : hA;
        float acc[24];
#pragma unroll
        for (int n = 0; n < 24; ++n) acc[n] = 0.f;
        for (int u = 0; u < ND; ++u) {
            const float wv = wrow[u];
#pragma unroll
            for (int n = 0; n < 24; ++n) acc[n] += wv * hin[u][n];
        }
#pragma unroll
        for (int n = 0; n < 24; ++n) hout[tid][n] = acc[n];
        __syncthreads();
    }
    float* outh = out + (size_t)NB * NR * 3;
#pragma unroll
    for (int bb = 0; bb < 8; ++bb) {
        const size_t base = ((size_t)((b0 + bb) * NR + r)) * (ND * 3);
#pragma unroll
        for (int it = 0; it < 3; ++it) {
            const int g = it * 256 + tid;
            outh[base + g] = hA[g / 3][bb * 3 + g % 3];
        }
    }
}

extern "C" void kernel_launch(void* const* d_in, const int* in_sizes, int n_in,
                              void* d_out, int out_size, void* d_ws, size_t ws_size,
                              hipStream_t stream) {
    const float* x        = (const float*)d_in[0];
    const float* W0       = (const float*)d_in[1];
    const float* Wh       = (const float*)d_in[2];
    const int*   type_ids = (const int*)d_in[3];
    const int*   res_idx  = (const int*)d_in[4];
    float* out = (float*)d_out;
    const int n_atoms = in_sizes[0] / (NB * 3);

    if (ws_size >= WS_NEEDED) {
        unsigned short* wsw = (unsigned short*)d_ws;
        conv_wh<<<(40 * 16 * 8 * 64 + 255) / 256, 256, 0, stream>>>(Wh, wsw);
        conv_w0<<<(20 * 16 * 64 + 255) / 256, 256, 0, stream>>>(W0, wsw);
        residues_mfma<<<NR * 4, 256, 0, stream>>>(x, wsw, type_ids, res_idx, out, n_atoms);
    } else {
        residues_fused_fb<<<NR * 16, 256, 0, stream>>>(x, W0, Wh, type_ids, res_idx, out, n_atoms);
    }
}

// Round 5
// 145.663 us; speedup vs baseline: 7.4277x; 1.0194x over previous
//
#include <hip/hip_runtime.h>

namespace {
constexpr int NB = 128;
constexpr int NR = 512;
constexpr int ND = 256;
constexpr int NA = 14;

using short8 = __attribute__((ext_vector_type(8))) short;
using f32x4  = __attribute__((ext_vector_type(4))) float;

// swizzled-weight workspace layout (ushort elements)
constexpr size_t WH_US  = (size_t)40 * 16 * 8 * 64 * 8;   // 2,621,440
constexpr size_t W0_OFF = WH_US;                          // W0 after Wh
constexpr size_t W0_US  = (size_t)20 * 16 * 64 * 8;       // 163,840
constexpr size_t WS_NEEDED = (WH_US + W0_US) * 2;         // bytes = 5,570,560

__device__ __forceinline__ unsigned short f2bf(float f) {
    unsigned int u = __float_as_uint(f);
    u = (u + 0x7FFFu + ((u >> 16) & 1u)) >> 16;           // RNE
    return (unsigned short)u;
}
}

// ---- converter: Wh fp32 -> bf16, A-fragment order ---------------------------
__global__ void conv_wh(const float* __restrict__ Wh, unsigned short* __restrict__ ws) {
    int g = blockIdx.x * 256 + threadIdx.x;
    if (g >= 40 * 16 * 8 * 64) return;
    const int lane = g & 63, kt = (g >> 6) & 7, mt = (g >> 9) & 15, tl = g >> 13;
    const int v = mt * 16 + (lane & 15);
    const int u0 = kt * 32 + (lane >> 4) * 8;
    const float* src = Wh + ((size_t)tl * ND + v) * ND + u0;
    unsigned short o[8];
#pragma unroll
    for (int j = 0; j < 8; ++j) o[j] = f2bf(src[j]);
    uint4 pk;
    pk.x = o[0] | ((unsigned)o[1] << 16); pk.y = o[2] | ((unsigned)o[3] << 16);
    pk.z = o[4] | ((unsigned)o[5] << 16); pk.w = o[6] | ((unsigned)o[7] << 16);
    *reinterpret_cast<uint4*>(ws + (size_t)g * 8) = pk;
}

__global__ void conv_w0(const float* __restrict__ W0, unsigned short* __restrict__ ws) {
    int g = blockIdx.x * 256 + threadIdx.x;
    if (g >= 20 * 16 * 64) return;
    const int lane = g & 63, mt = (g >> 6) & 15, t = g >> 10;
    const int v = mt * 16 + (lane & 15);
    const int a0 = (lane >> 4) * 8;
    unsigned short o[8];
#pragma unroll
    for (int j = 0; j < 8; ++j) {
        const int a = a0 + j;
        o[j] = (a < NA) ? f2bf(W0[((size_t)t * ND + v) * NA + a]) : (unsigned short)0;
    }
    uint4 pk;
    pk.x = o[0] | ((unsigned)o[1] << 16); pk.y = o[2] | ((unsigned)o[3] << 16);
    pk.z = o[4] | ((unsigned)o[5] << 16); pk.w = o[6] | ((unsigned)o[7] << 16);
    *reinterpret_cast<uint4*>(ws + W0_OFF + (size_t)g * 8) = pk;
}

// ---- main fused kernel ------------------------------------------------------
// block = (residue r, 32-batch column chunk) ; 96 GEMM columns n=(b-b0)*3+c
// 4 waves split M (v): wave w owns v in [64w, 64w+64)
__global__ __launch_bounds__(256, 3) void residues_mfma(
    const float* __restrict__ x, const unsigned short* __restrict__ wsw,
    const int* __restrict__ type_ids, const int* __restrict__ res_idx,
    float* __restrict__ out, int n_atoms)
{
    const int tid = threadIdx.x, lane = tid & 63, w = tid >> 6;
    const int r = blockIdx.x >> 2, b0 = (blockIdx.x & 3) * 32;
    const int ri = res_idx[r], t = type_ids[r];

    // HT[96][264] bf16 (row stride 528B). Aliased (disjoint lifetimes):
    //   dltT[96][40] bf16 @ byte 0..7679
    //   xs[32][48] f32    @ byte 8192..14335
    //   fst[96][132] f32  @ whole buffer (epilogue)
    __shared__ __align__(16) unsigned short HT[96 * 264];
    unsigned short* dltT = HT;
    float* xs = reinterpret_cast<float*>(HT + 4096);

    // hoist layer-0 A fragments: only depend on t -> overlap with x staging
    const unsigned short* w0b = wsw + W0_OFF + (size_t)t * (16 * 64 * 8);
    short8 a0[4];
#pragma unroll
    for (int mi = 0; mi < 4; ++mi)
        a0[mi] = *reinterpret_cast<const short8*>(w0b + (((w * 4 + mi) * 64) + lane) * 8);

    // ---- stage x rows vectorized: xs[bl][a*3+e], atoms ri..ri+15 clamped ----
    for (int task = tid; task < 32 * 16; task += 256) {
        const int bl = task >> 4, a = task & 15;
        int atom = ri + a; if (atom > n_atoms - 1) atom = n_atoms - 1;
        const float* src = x + ((size_t)(b0 + bl) * n_atoms + atom) * 3;
        xs[bl * 48 + a * 3 + 0] = src[0];
        xs[bl * 48 + a * 3 + 1] = src[1];
        xs[bl * 48 + a * 3 + 2] = src[2];
    }
    __syncthreads();

    // ---- dltT (bf16, k padded to 32 with zeros) + pos_ca from LDS ----------
    for (int i = tid; i < 96 * 32; i += 256) {
        const int n = i >> 5, k = i & 31;
        const int bl = n / 3, c = n % 3;
        float val = 0.f;
        if (k < NA) val = xs[bl * 48 + k * 3 + c] - xs[bl * 48 + 3 + c];
        dltT[n * 40 + k] = f2bf(val);
    }
    if (tid < 96) {
        const int bl = tid / 3, c = tid % 3;
        out[((size_t)(b0 + bl) * NR + r) * 3 + c] = xs[bl * 48 + 3 + c];
    }
    __syncthreads();

    f32x4 acc[4][6];
#pragma unroll
    for (int mi = 0; mi < 4; ++mi)
#pragma unroll
        for (int ni = 0; ni < 6; ++ni) acc[mi][ni] = f32x4{0.f, 0.f, 0.f, 0.f};

    // ---- layer 0: K=32 (padded), A hoisted, B from dltT --------------------
    {
        short8 bf[6];
#pragma unroll
        for (int ni = 0; ni < 6; ++ni)
            bf[ni] = *reinterpret_cast<const short8*>(&dltT[(ni * 16 + (lane & 15)) * 40 + (lane >> 4) * 8]);
#pragma unroll
        for (int mi = 0; mi < 4; ++mi)
#pragma unroll
            for (int ni = 0; ni < 6; ++ni)
                acc[mi][ni] = __builtin_amdgcn_mfma_f32_16x16x32_bf16(a0[mi], bf[ni], acc[mi][ni], 0, 0, 0);
    }
    __syncthreads();

    // ---- hidden layers: acc -> HT (bf16), then GEMM from HT ----------------
#pragma unroll 1
    for (int l = 0; l < 2; ++l) {
#pragma unroll
        for (int mi = 0; mi < 4; ++mi)
#pragma unroll
            for (int ni = 0; ni < 6; ++ni) {
                const int v0 = w * 64 + mi * 16 + (lane >> 4) * 4;
                const int n  = ni * 16 + (lane & 15);
                const unsigned lo = (unsigned)f2bf(acc[mi][ni][0]) | ((unsigned)f2bf(acc[mi][ni][1]) << 16);
                const unsigned hi = (unsigned)f2bf(acc[mi][ni][2]) | ((unsigned)f2bf(acc[mi][ni][3]) << 16);
                *reinterpret_cast<uint2*>(&HT[n * 264 + v0]) = make_uint2(lo, hi);
            }
        __syncthreads();

#pragma unroll
        for (int mi = 0; mi < 4; ++mi)
#pragma unroll
            for (int ni = 0; ni < 6; ++ni) acc[mi][ni] = f32x4{0.f, 0.f, 0.f, 0.f};

        const unsigned short* wl = wsw + (size_t)(t * 2 + l) * (16 * 8 * 64 * 8);
        for (int kt = 0; kt < 8; ++kt) {
            short8 a[4], bf[6];
#pragma unroll
            for (int mi = 0; mi < 4; ++mi)
                a[mi] = *reinterpret_cast<const short8*>(wl + ((((w * 4 + mi) * 8 + kt) * 64) + lane) * 8);
#pragma unroll
            for (int ni = 0; ni < 6; ++ni)
                bf[ni] = *reinterpret_cast<const short8*>(&HT[(ni * 16 + (lane & 15)) * 264 + kt * 32 + (lane >> 4) * 8]);
#pragma unroll
            for (int mi = 0; mi < 4; ++mi)
#pragma unroll
                for (int ni = 0; ni < 6; ++ni)
                    acc[mi][ni] = __builtin_amdgcn_mfma_f32_16x16x32_bf16(a[mi], bf[ni], acc[mi][ni], 0, 0, 0);
        }
        if (l == 0) __syncthreads();   // all waves done reading HT before rewrite
    }

    // ---- epilogue: fp32 restage through LDS, nontemporal f32x4 stores ------
    float* fst  = reinterpret_cast<float*>(HT);         // [96][132]
    float* outh = out + (size_t)NB * NR * 3;
#pragma unroll 1
    for (int p = 0; p < 2; ++p) {
        __syncthreads();
        if ((w >> 1) == p) {
            const int wl_ = w & 1;
#pragma unroll
            for (int mi = 0; mi < 4; ++mi)
#pragma unroll
                for (int ni = 0; ni < 6; ++ni) {
                    const int n = ni * 16 + (lane & 15);
#pragma unroll
                    for (int j = 0; j < 4; ++j) {
                        const int vl = wl_ * 64 + mi * 16 + (lane >> 4) * 4 + j;
                        fst[n * 132 + vl] = acc[mi][ni][j];
                    }
                }
        }
        __syncthreads();
#pragma unroll
        for (int i = 0; i < 12; ++i) {
            const int idx = tid + i * 256;        // 0..3071
            const int bl = idx / 96, g = idx % 96;
            f32x4 v4;
#pragma unroll
            for (int e = 0; e < 4; ++e) {
                const int f = 4 * g + e, c = f % 3, vp = f / 3;
                v4[e] = fst[(bl * 3 + c) * 132 + vp];
            }
            __builtin_nontemporal_store(v4,
                reinterpret_cast<f32x4*>(&outh[(((size_t)(b0 + bl) * NR + r) * (ND * 3)) + p * 384 + 4 * g]));
        }
    }
}

// ---- fallback (round-2 verified VALU kernel) if ws too small ---------------
__global__ __launch_bounds__(256, 3) void residues_fused_fb(
    const float* __restrict__ x, const float* __restrict__ W0,
    const float* __restrict__ Wh, const int* __restrict__ type_ids,
    const int* __restrict__ res_idx, float* __restrict__ out, int n_atoms)
{
    const int tid = threadIdx.x;
    const int r = blockIdx.x >> 4;
    const int b0 = (blockIdx.x & 15) * 8;
    const int ri = res_idx[r], t = type_ids[r];
    __shared__ float dlt[NA][24];
    __shared__ float hA[ND][24];
    __shared__ float hB[ND][24];
    for (int idx = tid; idx < 8 * NA * 3; idx += 256) {
        const int bb = idx / (NA * 3), rem = idx % (NA * 3);
        const int a = rem / 3, c = rem % 3, b = b0 + bb;
        int ca = ri + a; if (ca > n_atoms - 1) ca = n_atoms - 1;
        const float root = x[((size_t)b * n_atoms + (ri + 1)) * 3 + c];
        dlt[a][bb * 3 + c] = x[((size_t)b * n_atoms + ca) * 3 + c] - root;
        if (a == 0) out[((size_t)b * NR + r) * 3 + c] = root;
    }
    __syncthreads();
    {
        const float* w0row = W0 + ((size_t)t * ND + tid) * NA;
        float acc[24];
#pragma unroll
        for (int n = 0; n < 24; ++n) acc[n] = 0.f;
#pragma unroll
        for (int a = 0; a < NA; ++a) {
            const float wv = w0row[a];
#pragma unroll
            for (int n = 0; n < 24; ++n) acc[n] += wv * dlt[a][n];
        }
#pragma unroll
        for (int n = 0; n < 24; ++n) hA[tid][n] = acc[n];
    }
    __syncthreads();
    const float* whbase = Wh + (size_t)t * 2 * ND * ND;
#pragma unroll
    for (int l = 0; l < 2; ++l) {
        const float* wrow = whbase + ((size_t)l * ND + tid) * ND;
        const float (*hin)[24] = (l == 0) ? hA : hB;
        float (*hout)[24]      = (l == 0) ? hB : hA;
        float acc[24];
#pragma unroll
        for (int n = 0; n < 24; ++n) acc[n] = 0.f;
        for (int u = 0; u < ND; ++u) {
            const float wv = wrow[u];
#pragma unroll
            for (int n = 0; n < 24; ++n) acc[n] += wv * hin[u][n];
        }
#pragma unroll
        for (int n = 0; n < 24; ++n) hout[tid][n] = acc[n];
        __syncthreads();
    }
    float* outh = out + (size_t)NB * NR * 3;
#pragma unroll
    for (int bb = 0; bb < 8; ++bb) {
        const size_t base = ((size_t)((b0 + bb) * NR + r)) * (ND * 3);
#pragma unroll
        for (int it = 0; it < 3; ++it) {
            const int g = it * 256 + tid;
            outh[base + g] = hA[g / 3][bb * 3 + g % 3];
        }
    }
}

extern "C" void kernel_launch(void* const* d_in, const int* in_sizes, int n_in,
                              void* d_out, int out_size, void* d_ws, size_t ws_size,
                              hipStream_t stream) {
    const float* x        = (const float*)d_in[0];
    const float* W0       = (const float*)d_in[1];
    const float* Wh       = (const float*)d_in[2];
    const int*   type_ids = (const int*)d_in[3];
    const int*   res_idx  = (const int*)d_in[4];
    float* out = (float*)d_out;
    const int n_atoms = in_sizes[0] / (NB * 3);

    if (ws_size >= WS_NEEDED) {
        unsigned short* wsw = (unsigned short*)d_ws;
        conv_wh<<<(40 * 16 * 8 * 64 + 255) / 256, 256, 0, stream>>>(Wh, wsw);
        conv_w0<<<(20 * 16 * 64 + 255) / 256, 256, 0, stream>>>(W0, wsw);
        residues_mfma<<<NR * 4, 256, 0, stream>>>(x, wsw, type_ids, res_idx, out, n_atoms);
    } else {
        residues_fused_fb<<<NR * 16, 256, 0, stream>>>(x, W0, Wh, type_ids, res_idx, out, n_atoms);
    }
}